// Round 10
// baseline (986.476 us; speedup 1.0000x reference)
//
#include <hip/hip_runtime.h>

#define HW 262144
#define WID 512
#define PLANES 48
#define NCH 3
#define PAD 11
#define FW 23
#define XS 92   // xs/hs row stride (floats): 92%32=28 -> per-row bank phase rotation
#define NSUB 16 // histogram sub-blocks per plane

__device__ __forceinline__ float uniform_f(float v) {
  return __uint_as_float((unsigned)__builtin_amdgcn_readfirstlane((int)__float_as_uint(v)));
}

// ---------- stage-1 histogram: 512 thr, 8 f4 in flight/thread -> LDS hist -> u16 partial ----------
__global__ __launch_bounds__(512, 4) void hist1_kernel(const float* __restrict__ x,
                                                       ushort* __restrict__ part) {
  __shared__ int h[8192];
  const int p = blockIdx.x, s = blockIdx.y, tid = threadIdx.x;
  for (int i = tid; i < 8192; i += 512) h[i] = 0;
  __syncthreads();
  const float4* xv = (const float4*)(x + (size_t)p * HW + (size_t)s * (HW / NSUB));
  float4 a[8];
#pragma unroll
  for (int q = 0; q < 8; ++q) a[q] = xv[tid + q * 512];
#define H1(c) { int bin = (int)(((c) + 8.0f) * 512.0f); bin = min(max(bin, 0), 8191); atomicAdd(&h[bin], 1); }
#pragma unroll
  for (int q = 0; q < 8; ++q) { H1(a[q].x); H1(a[q].y); H1(a[q].z); H1(a[q].w); }
#undef H1
  __syncthreads();
  uint4* out = (uint4*)(part + ((size_t)p * NSUB + s) * 8192);
  for (int k = tid; k < 1024; k += 512) {
    int4 c = *(const int4*)&h[k * 8];
    int4 d = *(const int4*)&h[k * 8 + 4];
    uint4 w;
    w.x = (unsigned)c.x | ((unsigned)c.y << 16);
    w.y = (unsigned)c.z | ((unsigned)c.w << 16);
    w.z = (unsigned)d.x | ((unsigned)d.y << 16);
    w.w = (unsigned)d.z | ((unsigned)d.w << 16);
    out[k] = w;
  }
}

// ---------- conv + claim-elected per-plane median select ----------
// First block of each plane to arrive (atomicAdd ticket==0) computes the median from the
// u16 partials (register-resident bins) and release-publishes med[z] via the L3 coherence
// point. Other blocks acquire-spin on med[z]!=0 (med is provably never +0.0f).
// Deadlock-free for ANY dispatch order: the claimer has no upstream dependency.
__global__ __launch_bounds__(256) void conv_kernel(const float* __restrict__ x,
                                                   const float* __restrict__ mask,
                                                   const float* __restrict__ kern,
                                                   const ushort* __restrict__ part,
                                                   float* __restrict__ med,
                                                   int* __restrict__ claim,
                                                   float* __restrict__ res) {
  __shared__ float xs[86 * XS];  // 31648 B; doubles as scan scratch during select
  __shared__ float s_k1[FW];
  __shared__ float s_med;
  __shared__ int s_tk, s_chunk, s_base;
  const int tid = threadIdx.x;

  // bijective XCD swizzle: 3072 blocks, 8 XCDs, 384 contiguous tiles (= 6 planes) per XCD
  const int tt = (blockIdx.x & 7) * 384 + (blockIdx.x >> 3);
  const int z = tt >> 6;
  const int tby = (tt >> 3) & 7, tbx = tt & 7;
  const int n = z / NCH;

  if (tid == 0) s_tk = atomicAdd(&claim[z], 1);
  if (tid < FW) s_k1[tid] = kern[tid * FW + PAD] / sqrtf(kern[PAD * FW + PAD]);
  __syncthreads();

  if (s_tk == 0) {
    // elected: median select for plane z. bins t*32..t*32+31 live in registers.
    int bins[32];
#pragma unroll
    for (int j = 0; j < 32; ++j) bins[j] = 0;
#pragma unroll
    for (int s = 0; s < NSUB; ++s) {
      const uint4* q = (const uint4*)(part + (size_t)z * NSUB * 8192 + (size_t)s * 8192 + tid * 32);
#pragma unroll
      for (int u = 0; u < 4; ++u) {
        uint4 v = q[u];
        bins[u * 8 + 0] += (int)(v.x & 0xffff); bins[u * 8 + 1] += (int)(v.x >> 16);
        bins[u * 8 + 2] += (int)(v.y & 0xffff); bins[u * 8 + 3] += (int)(v.y >> 16);
        bins[u * 8 + 4] += (int)(v.z & 0xffff); bins[u * 8 + 5] += (int)(v.z >> 16);
        bins[u * 8 + 6] += (int)(v.w & 0xffff); bins[u * 8 + 7] += (int)(v.w >> 16);
      }
    }
    int mysum = 0;
#pragma unroll
    for (int j = 0; j < 32; ++j) mysum += bins[j];
    int* incl = (int*)xs;  // xs free at this point
    incl[tid] = mysum;
    __syncthreads();
    for (int off = 1; off < 256; off <<= 1) {
      int v = (tid >= off) ? incl[tid - off] : 0;
      __syncthreads();
      incl[tid] += v;
      __syncthreads();
    }
    const int rank = 131072;  // 1-based rank of sorted idx (HW-1)/2
    {
      int excl = incl[tid] - mysum;
      if (excl < rank && rank <= incl[tid]) { s_chunk = tid; s_base = rank - excl; }
    }
    __syncthreads();
    if (tid == s_chunk) {
      int cum = 0, bfound = -1;
#pragma unroll
      for (int j = 0; j < 32; ++j) {
        cum += bins[j];
        if (bfound < 0 && cum >= s_base) bfound = j;
      }
      int bin = tid * 32 + bfound;
      float mval = -8.0f + ((float)bin + 0.5f) * 0.001953125f + 0.2f;  // never exactly +0.0f
      __hip_atomic_store(&med[z], mval, __ATOMIC_RELEASE, __HIP_MEMORY_SCOPE_AGENT);
    }
    __syncthreads();  // incl scratch dead before staging reuses xs
  }

  // converge: everyone (claimer included) reads the gate
  if (tid == 0) {
    int b;
    do {
      b = __hip_atomic_load((const int*)&med[z], __ATOMIC_ACQUIRE, __HIP_MEMORY_SCOPE_AGENT);
      if (b == 0) __builtin_amdgcn_s_sleep(2);
    } while (b == 0);
    s_med = __int_as_float(b);
  }
  __syncthreads();

  float k1[FW];
#pragma unroll
  for (int t = 0; t < FW; ++t) k1[t] = uniform_f(s_k1[t]);
  const float m_med = uniform_f(s_med);

  const int gr0 = tby * 64 - PAD;
  const int gc0 = tbx * 64 - PAD;
  const float* xb = x + (size_t)z * HW;
  const float* mb = mask + (size_t)n * HW;
  for (int i = tid; i < 86 * 86; i += 256) {
    int r = i / 86, c = i - r * 86;
    int gr = min(max(gr0 + r, 0), WID - 1);
    int gc = min(max(gc0 + c, 0), WID - 1);
    int g = gr * WID + gc;
    float xv = xb[g], mv = mb[g];
    xs[r * XS + c] = fmaf(mv, xv - m_med, m_med);
  }
  __syncthreads();

  // horizontal: 86 rows x 8 groups of 8 outputs = 688 tasks, into registers
  float ah[3][8];
#pragma unroll
  for (int it = 0; it < 3; ++it) {
    const int g = tid + (it << 8);
    if (g < 86 * 8) {
      const int r = g >> 3, c0 = (g & 7) << 3;
      const float* row = &xs[r * XS + c0];
      float w[32];
#pragma unroll
      for (int q = 0; q < 8; ++q) *(float4*)&w[q * 4] = *(const float4*)(row + q * 4);
#pragma unroll
      for (int j = 0; j < 8; ++j) ah[it][j] = 0.f;
#pragma unroll
      for (int t = 0; t < FW; ++t) {
        const float k = k1[t];
#pragma unroll
        for (int j = 0; j < 8; ++j) ah[it][j] = fmaf(k, w[t + j], ah[it][j]);
      }
    }
  }

  // save my central xp values to regs before the overlay destroys xs
  const int ct = (tid & 15) << 2;
  const int rt = (tid >> 4) << 2;
  float4 xpA[4], xpB[4];
#pragma unroll
  for (int j = 0; j < 4; ++j) {
    const float* xr = &xs[(rt + j + PAD) * XS + ct];
    xpA[j] = *(const float4*)(xr + 8);    // .w   = xp at col ct+11
    xpB[j] = *(const float4*)(xr + 12);   // .xyz = xp at cols ct+12..14
  }
  __syncthreads();  // all xs reads complete -> safe to overwrite with hs

#pragma unroll
  for (int it = 0; it < 3; ++it) {
    const int g = tid + (it << 8);
    if (g < 86 * 8) {
      const int r = g >> 3, c0 = (g & 7) << 3;
      *(float4*)&xs[r * XS + c0] = make_float4(ah[it][0], ah[it][1], ah[it][2], ah[it][3]);
      *(float4*)&xs[r * XS + c0 + 4] = make_float4(ah[it][4], ah[it][5], ah[it][6], ah[it][7]);
    }
  }
  __syncthreads();

  // vertical: 4x4 micro-tile per thread, reading hs overlay at stride XS
  float4 acc[4];
#pragma unroll
  for (int j = 0; j < 4; ++j) acc[j] = make_float4(0.f, 0.f, 0.f, 0.f);
#pragma unroll
  for (int tp = 0; tp < 26; ++tp) {
    float4 v = *(const float4*)&xs[(rt + tp) * XS + ct];
    const int jlo = (tp - 22 > 0) ? (tp - 22) : 0;
    const int jhi = (tp < 3) ? tp : 3;
#pragma unroll
    for (int j = jlo; j <= jhi; ++j) {
      float k = k1[tp - j];
      acc[j].x = fmaf(k, v.x, acc[j].x);
      acc[j].y = fmaf(k, v.y, acc[j].y);
      acc[j].z = fmaf(k, v.z, acc[j].z);
      acc[j].w = fmaf(k, v.w, acc[j].w);
    }
  }

  float* rb = res + (size_t)z * HW + (size_t)(tby * 64 + rt) * WID + tbx * 64 + ct;
#pragma unroll
  for (int j = 0; j < 4; ++j) {
    float4 o;
    o.x = 4.0f * (xpA[j].w - acc[j].x);
    o.y = 4.0f * (xpB[j].x - acc[j].y);
    o.z = 4.0f * (xpB[j].y - acc[j].z);
    o.w = 4.0f * (xpB[j].z - acc[j].w);
    *(float4*)(rb + (size_t)j * WID) = o;
  }
}

// ---------- stage-2 histogram of res: 512 thr, 8 f4 in flight/thread ----------
__global__ __launch_bounds__(512, 4) void hist_kernel(const float* __restrict__ res,
                                                      ushort* __restrict__ part) {
  __shared__ int h[8192];
  const int p = blockIdx.x, s = blockIdx.y, tid = threadIdx.x;
  for (int i = tid; i < 8192; i += 512) h[i] = 0;
  __syncthreads();
  const float4* rv = (const float4*)(res + (size_t)p * HW + (size_t)s * (HW / NSUB));
  float4 a[8];
#pragma unroll
  for (int q = 0; q < 8; ++q) a[q] = rv[tid + q * 512];
#define HADD(c) { int bin = (int)((c) * 256.0f) + 4096; bin = min(max(bin, 0), 8191); atomicAdd(&h[bin], 1); }
#pragma unroll
  for (int q = 0; q < 8; ++q) { HADD(a[q].x); HADD(a[q].y); HADD(a[q].z); HADD(a[q].w); }
#undef HADD
  __syncthreads();
  uint4* out = (uint4*)(part + ((size_t)p * NSUB + s) * 8192);
  for (int k = tid; k < 1024; k += 512) {
    int4 c = *(const int4*)&h[k * 8];
    int4 d = *(const int4*)&h[k * 8 + 4];
    uint4 w;
    w.x = (unsigned)c.x | ((unsigned)c.y << 16);
    w.y = (unsigned)c.z | ((unsigned)c.w << 16);
    w.z = (unsigned)d.x | ((unsigned)d.y << 16);
    w.w = (unsigned)d.z | ((unsigned)d.w << 16);
    out[k] = w;
  }
}

// ---------- final normalize + claim-elected per-plane percentile select ----------
// Same election pattern as conv: first block of each plane (128 blocks/plane) computes the
// 4-rank select from partials and release-publishes inv[z] (gate, provably nonzero) + lo[z].
__global__ __launch_bounds__(256) void final_kernel(float* __restrict__ res,
                                                    const float* __restrict__ mask,
                                                    const ushort* __restrict__ part,
                                                    float* __restrict__ lo,
                                                    float* __restrict__ inv,
                                                    int* __restrict__ claim) {
  __shared__ int incl[256];
  __shared__ int s_tk, s_chunk, s_base;
  __shared__ float s_v[4];
  __shared__ float s_lo, s_inv;
  const int tid = threadIdx.x;
  const int base = blockIdx.x * 512 + tid;  // f4 units; block fully inside one plane
  const int z = base >> 16;
  const int n = z / NCH;

  if (tid == 0) s_tk = atomicAdd(&claim[z], 1);
  __syncthreads();

  if (s_tk == 0) {
    int bins[32];
#pragma unroll
    for (int j = 0; j < 32; ++j) bins[j] = 0;
#pragma unroll
    for (int s = 0; s < NSUB; ++s) {
      const uint4* q = (const uint4*)(part + (size_t)z * NSUB * 8192 + (size_t)s * 8192 + tid * 32);
#pragma unroll
      for (int u = 0; u < 4; ++u) {
        uint4 v = q[u];
        bins[u * 8 + 0] += (int)(v.x & 0xffff); bins[u * 8 + 1] += (int)(v.x >> 16);
        bins[u * 8 + 2] += (int)(v.y & 0xffff); bins[u * 8 + 3] += (int)(v.y >> 16);
        bins[u * 8 + 4] += (int)(v.z & 0xffff); bins[u * 8 + 5] += (int)(v.z >> 16);
        bins[u * 8 + 6] += (int)(v.w & 0xffff); bins[u * 8 + 7] += (int)(v.w >> 16);
      }
    }
    int mysum = 0;
#pragma unroll
    for (int j = 0; j < 32; ++j) mysum += bins[j];
    incl[tid] = mysum;
    __syncthreads();
    for (int off = 1; off < 256; off <<= 1) {
      int v = (tid >= off) ? incl[tid - off] : 0;
      __syncthreads();
      incl[tid] += v;
      __syncthreads();
    }
    // 1-based ranks: lo -> 7865,7866 (frac .29); hi -> 254279,254280 (frac .71)
    const int ranks[4] = {7865, 7866, 254279, 254280};
#pragma unroll
    for (int r = 0; r < 4; ++r) {
      const int rank = ranks[r];
      int excl = incl[tid] - mysum;
      if (excl < rank && rank <= incl[tid]) { s_chunk = tid; s_base = rank - excl; }
      __syncthreads();
      if (tid == s_chunk) {
        int cum = 0, bfound = -1;
#pragma unroll
        for (int j = 0; j < 32; ++j) {
          cum += bins[j];
          if (bfound < 0 && cum >= s_base) bfound = j;
        }
        s_v[r] = (float)(tid * 32 + bfound - 4096) * 0.00390625f;
      }
      __syncthreads();
    }
    if (tid == 0) {
      const double fl = 0.29, fh = 0.71;
      double lov = (double)s_v[0] + fl * ((double)s_v[1] - (double)s_v[0]);
      double hiv = (double)s_v[2] + fh * ((double)s_v[3] - (double)s_v[2]);
      float lof = (float)lov;
      float invf = (float)(1.0 / (hiv - lov));  // > 1/32, never 0-bit pattern
      __hip_atomic_store(&lo[z], lof, __ATOMIC_RELAXED, __HIP_MEMORY_SCOPE_AGENT);
      __hip_atomic_store(&inv[z], invf, __ATOMIC_RELEASE, __HIP_MEMORY_SCOPE_AGENT);
    }
  }

  if (tid == 0) {
    int b;
    do {
      b = __hip_atomic_load((const int*)&inv[z], __ATOMIC_ACQUIRE, __HIP_MEMORY_SCOPE_AGENT);
      if (b == 0) __builtin_amdgcn_s_sleep(2);
    } while (b == 0);
    s_inv = __int_as_float(b);
    s_lo = __hip_atomic_load(&lo[z], __ATOMIC_RELAXED, __HIP_MEMORY_SCOPE_AGENT);
  }
  __syncthreads();

  const float l = uniform_f(s_lo);
  const float iv = uniform_f(s_inv);
  const int h0 = base & 65535;
  float4* rz = (float4*)res;
  const float4* mz = (const float4*)mask + (size_t)n * 65536;
  float4 r0 = rz[base], r1 = rz[base + 256];
  float4 m0 = mz[h0], m1 = mz[h0 + 256];
  float4 o0, o1;
  o0.x = (r0.x - l) * iv * m0.x;  o0.y = (r0.y - l) * iv * m0.y;
  o0.z = (r0.z - l) * iv * m0.z;  o0.w = (r0.w - l) * iv * m0.w;
  o1.x = (r1.x - l) * iv * m1.x;  o1.y = (r1.y - l) * iv * m1.y;
  o1.z = (r1.z - l) * iv * m1.z;  o1.w = (r1.w - l) * iv * m1.w;
  rz[base] = o0;
  rz[base + 256] = o1;
}

extern "C" void kernel_launch(void* const* d_in, const int* in_sizes, int n_in,
                              void* d_out, int out_size, void* d_ws, size_t ws_size,
                              hipStream_t stream) {
  (void)in_sizes; (void)n_in; (void)out_size; (void)ws_size;
  const float* x = (const float*)d_in[0];
  const float* mask = (const float*)d_in[1];
  const float* kern = (const float*)d_in[2];
  float* out = (float*)d_out;  // doubles as res scratch

  // partial histograms: PLANES*NSUB rows of 8192 u16 = 12.58 MB, reused by both stages
  ushort* part = (ushort*)d_ws;
  float* med = (float*)(part + (size_t)PLANES * NSUB * 8192);
  float* inv = med + PLANES;
  int* claim1 = (int*)(inv + PLANES);
  int* claim2 = claim1 + PLANES;
  float* lo = (float*)(claim2 + PLANES);

  // re-poison gates + claim tickets every replay (med/inv/claim1/claim2 contiguous)
  hipMemsetAsync(med, 0, 4 * PLANES * sizeof(int), stream);
  hist1_kernel<<<dim3(PLANES, NSUB), 512, 0, stream>>>(x, part);
  conv_kernel<<<dim3(3072), 256, 0, stream>>>(x, mask, kern, part, med, claim1, out);
  hist_kernel<<<dim3(PLANES, NSUB), 512, 0, stream>>>(out, part);
  final_kernel<<<dim3(6144), 256, 0, stream>>>(out, mask, part, lo, inv, claim2);
}

// Round 12
// 187.863 us; speedup vs baseline: 5.2510x; 5.2510x over previous
//
#include <hip/hip_runtime.h>

#define HW 262144
#define WID 512
#define PLANES 48
#define NCH 3
#define PAD 11
#define FW 23
#define XS 92   // xs/hs row stride (floats): 92%32=28 -> per-row bank phase rotation
#define NSUB 16 // histogram sub-blocks per plane

__device__ __forceinline__ float uniform_f(float v) {
  return __uint_as_float((unsigned)__builtin_amdgcn_readfirstlane((int)__float_as_uint(v)));
}

// ---------- stage-1 histogram: 512 thr, 8 f4 in flight/thread -> LDS hist -> u16 partial ----------
__global__ __launch_bounds__(512, 4) void hist1_kernel(const float* __restrict__ x,
                                                       ushort* __restrict__ part) {
  __shared__ int h[8192];
  const int p = blockIdx.x, s = blockIdx.y, tid = threadIdx.x;
  for (int i = tid; i < 8192; i += 512) h[i] = 0;
  __syncthreads();
  const float4* xv = (const float4*)(x + (size_t)p * HW + (size_t)s * (HW / NSUB));
  float4 a[8];
#pragma unroll
  for (int q = 0; q < 8; ++q) a[q] = xv[tid + q * 512];
#define H1(c) { int bin = (int)(((c) + 8.0f) * 512.0f); bin = min(max(bin, 0), 8191); atomicAdd(&h[bin], 1); }
#pragma unroll
  for (int q = 0; q < 8; ++q) { H1(a[q].x); H1(a[q].y); H1(a[q].z); H1(a[q].w); }
#undef H1
  __syncthreads();
  uint4* out = (uint4*)(part + ((size_t)p * NSUB + s) * 8192);
  for (int k = tid; k < 1024; k += 512) {
    int4 c = *(const int4*)&h[k * 8];
    int4 d = *(const int4*)&h[k * 8 + 4];
    uint4 w;
    w.x = (unsigned)c.x | ((unsigned)c.y << 16);
    w.y = (unsigned)c.z | ((unsigned)c.w << 16);
    w.z = (unsigned)d.x | ((unsigned)d.y << 16);
    w.w = (unsigned)d.z | ((unsigned)d.w << 16);
    out[k] = w;
  }
}

// ---------- median select over summed partials (+ k1 prep piggybacked) ----------
__global__ __launch_bounds__(256) void scan_med_kernel(const ushort* __restrict__ part,
                                                       float* __restrict__ med,
                                                       const float* __restrict__ kern,
                                                       float* __restrict__ k1g) {
  __shared__ int hsum[8192];
  __shared__ int incl[256];
  __shared__ int s_chunk, s_base;
  const int p = blockIdx.x, t = threadIdx.x;
  if (p == 0 && t < FW) k1g[t] = kern[t * FW + PAD] / sqrtf(kern[PAD * FW + PAD]);
  const uint4* pr = (const uint4*)(part + (size_t)p * NSUB * 8192);
  for (int idx = t; idx < 1024; idx += 256) {
    int a0=0,a1=0,a2=0,a3=0,a4=0,a5=0,a6=0,a7=0;
#pragma unroll
    for (int s = 0; s < NSUB; ++s) {
      uint4 v = pr[(size_t)s * 1024 + idx];
      a0 += (int)(v.x & 0xffff); a1 += (int)(v.x >> 16);
      a2 += (int)(v.y & 0xffff); a3 += (int)(v.y >> 16);
      a4 += (int)(v.z & 0xffff); a5 += (int)(v.z >> 16);
      a6 += (int)(v.w & 0xffff); a7 += (int)(v.w >> 16);
    }
    int* hb = &hsum[idx * 8];
    hb[0]=a0; hb[1]=a1; hb[2]=a2; hb[3]=a3; hb[4]=a4; hb[5]=a5; hb[6]=a6; hb[7]=a7;
  }
  __syncthreads();
  int mysum = 0;
#pragma unroll
  for (int j = 0; j < 32; j += 4) {
    int4 v = *(const int4*)&hsum[t * 32 + j];
    mysum += v.x + v.y + v.z + v.w;
  }
  incl[t] = mysum;
  __syncthreads();
  for (int off = 1; off < 256; off <<= 1) {
    int v = (t >= off) ? incl[t - off] : 0;
    __syncthreads();
    incl[t] += v;
    __syncthreads();
  }
  const int rank = 131072;  // 1-based rank of sorted idx (HW-1)/2
  {
    int excl = incl[t] - mysum;
    if (excl < rank && rank <= incl[t]) { s_chunk = t; s_base = rank - excl; }
  }
  __syncthreads();
  if (t < 64) {
    const int c = s_chunk, base = s_base;
    int cnt = (t < 32) ? hsum[c * 32 + t] : 0;
    int pfx = cnt;
#pragma unroll
    for (int off = 1; off < 32; off <<= 1) {
      int u = __shfl_up(pfx, off, 64);
      if (t >= off) pfx += u;
    }
    unsigned long long m = __ballot(t < 32 && pfx >= base);
    int bin = c * 32 + (__ffsll((long long)m) - 1);
    if (t == 0) med[p] = -8.0f + ((float)bin + 0.5f) * 0.001953125f + 0.2f;
  }
}

// ---------- separable 23x23 conv, register-tiled, hs overlaid on xs ----------
// 1D grid 3072 with bijective XCD swizzle: each XCD gets 384 contiguous tiles (= 6 planes)
// so halo/mask re-reads hit that XCD's L2, and plane z's res output lives in XCD z/6's L2.
__global__ __launch_bounds__(256) void conv_kernel(const float* __restrict__ x,
                                                   const float* __restrict__ mask,
                                                   const float* __restrict__ k1g,
                                                   const float* __restrict__ med,
                                                   float* __restrict__ res) {
  __shared__ float xs[86 * XS];  // 31648 B
  const int tid = threadIdx.x;

  // bijective swizzle: 3072 blocks, 8 XCDs, 384 per chunk (3072 % 8 == 0)
  const int tt = (blockIdx.x & 7) * 384 + (blockIdx.x >> 3);
  const int z = tt >> 6;                    // plane 0..47
  const int tby = (tt >> 3) & 7, tbx = tt & 7;
  const int n = z / NCH;

  float k1[FW];
#pragma unroll
  for (int t = 0; t < FW; ++t) k1[t] = uniform_f(k1g[t]);

  const float m_med = uniform_f(med[z]);
  const int gr0 = tby * 64 - PAD;
  const int gc0 = tbx * 64 - PAD;
  const float* xb = x + (size_t)z * HW;
  const float* mb = mask + (size_t)n * HW;
  for (int i = tid; i < 86 * 86; i += 256) {
    int r = i / 86, c = i - r * 86;
    int gr = min(max(gr0 + r, 0), WID - 1);
    int gc = min(max(gc0 + c, 0), WID - 1);
    int g = gr * WID + gc;
    float xv = xb[g], mv = mb[g];
    xs[r * XS + c] = fmaf(mv, xv - m_med, m_med);
  }
  __syncthreads();

  // horizontal: 86 rows x 8 groups of 8 outputs = 688 tasks, into registers
  float ah[3][8];
#pragma unroll
  for (int it = 0; it < 3; ++it) {
    const int g = tid + (it << 8);
    if (g < 86 * 8) {
      const int r = g >> 3, c0 = (g & 7) << 3;
      const float* row = &xs[r * XS + c0];
      float w[32];
#pragma unroll
      for (int q = 0; q < 8; ++q) *(float4*)&w[q * 4] = *(const float4*)(row + q * 4);
#pragma unroll
      for (int j = 0; j < 8; ++j) ah[it][j] = 0.f;
#pragma unroll
      for (int t = 0; t < FW; ++t) {
        const float k = k1[t];
#pragma unroll
        for (int j = 0; j < 8; ++j) ah[it][j] = fmaf(k, w[t + j], ah[it][j]);
      }
    }
  }

  // save my central xp values to regs before the overlay destroys xs
  const int ct = (tid & 15) << 2;
  const int rt = (tid >> 4) << 2;
  float4 xpA[4], xpB[4];
#pragma unroll
  for (int j = 0; j < 4; ++j) {
    const float* xr = &xs[(rt + j + PAD) * XS + ct];
    xpA[j] = *(const float4*)(xr + 8);    // .w   = xp at col ct+11
    xpB[j] = *(const float4*)(xr + 12);   // .xyz = xp at cols ct+12..14
  }
  __syncthreads();  // all xs reads complete -> safe to overwrite with hs

#pragma unroll
  for (int it = 0; it < 3; ++it) {
    const int g = tid + (it << 8);
    if (g < 86 * 8) {
      const int r = g >> 3, c0 = (g & 7) << 3;
      *(float4*)&xs[r * XS + c0] = make_float4(ah[it][0], ah[it][1], ah[it][2], ah[it][3]);
      *(float4*)&xs[r * XS + c0 + 4] = make_float4(ah[it][4], ah[it][5], ah[it][6], ah[it][7]);
    }
  }
  __syncthreads();

  // vertical: 4x4 micro-tile per thread, reading hs overlay at stride XS
  float4 acc[4];
#pragma unroll
  for (int j = 0; j < 4; ++j) acc[j] = make_float4(0.f, 0.f, 0.f, 0.f);
#pragma unroll
  for (int tp = 0; tp < 26; ++tp) {
    float4 v = *(const float4*)&xs[(rt + tp) * XS + ct];
    const int jlo = (tp - 22 > 0) ? (tp - 22) : 0;
    const int jhi = (tp < 3) ? tp : 3;
#pragma unroll
    for (int j = jlo; j <= jhi; ++j) {
      float k = k1[tp - j];
      acc[j].x = fmaf(k, v.x, acc[j].x);
      acc[j].y = fmaf(k, v.y, acc[j].y);
      acc[j].z = fmaf(k, v.z, acc[j].z);
      acc[j].w = fmaf(k, v.w, acc[j].w);
    }
  }

  float* rb = res + (size_t)z * HW + (size_t)(tby * 64 + rt) * WID + tbx * 64 + ct;
#pragma unroll
  for (int j = 0; j < 4; ++j) {
    float4 o;
    o.x = 4.0f * (xpA[j].w - acc[j].x);
    o.y = 4.0f * (xpB[j].x - acc[j].y);
    o.z = 4.0f * (xpB[j].y - acc[j].z);
    o.w = 4.0f * (xpB[j].z - acc[j].w);
    *(float4*)(rb + (size_t)j * WID) = o;
  }
}

// ---------- stage-2 histogram of res: 512 thr, 8 f4 in flight/thread ----------
// 1D grid 768 with XCD-affinity swizzle: blocks reading plane p land on XCD p/6,
// where conv just wrote plane p's res (L2-hot).
__global__ __launch_bounds__(512, 4) void hist_kernel(const float* __restrict__ res,
                                                      ushort* __restrict__ part) {
  __shared__ int h[8192];
  const int b = blockIdx.x;               // 768
  const int xcd = b & 7, idx = b >> 3;    // idx 0..95
  const int p = xcd * 6 + (idx >> 4);     // 6 planes per XCD
  const int s = idx & 15;
  const int tid = threadIdx.x;
  for (int i = tid; i < 8192; i += 512) h[i] = 0;
  __syncthreads();
  const float4* rv = (const float4*)(res + (size_t)p * HW + (size_t)s * (HW / NSUB));
  float4 a[8];
#pragma unroll
  for (int q = 0; q < 8; ++q) a[q] = rv[tid + q * 512];
#define HADD(c) { int bin = (int)((c) * 256.0f) + 4096; bin = min(max(bin, 0), 8191); atomicAdd(&h[bin], 1); }
#pragma unroll
  for (int q = 0; q < 8; ++q) { HADD(a[q].x); HADD(a[q].y); HADD(a[q].z); HADD(a[q].w); }
#undef HADD
  __syncthreads();
  uint4* out = (uint4*)(part + ((size_t)p * NSUB + s) * 8192);
  for (int k = tid; k < 1024; k += 512) {
    int4 c = *(const int4*)&h[k * 8];
    int4 d = *(const int4*)&h[k * 8 + 4];
    uint4 w;
    w.x = (unsigned)c.x | ((unsigned)c.y << 16);
    w.y = (unsigned)c.z | ((unsigned)c.w << 16);
    w.z = (unsigned)d.x | ((unsigned)d.y << 16);
    w.w = (unsigned)d.z | ((unsigned)d.w << 16);
    out[k] = w;
  }
}

// ---------- percentile select over summed partials ----------
__global__ __launch_bounds__(256) void pct_kernel(const ushort* __restrict__ part,
                                                  float* __restrict__ lo_out,
                                                  float* __restrict__ inv_out) {
  __shared__ int hsum[8192];
  __shared__ int incl[256];
  __shared__ int s_chunk, s_base;
  __shared__ float s_v[4];
  const int p = blockIdx.x, t = threadIdx.x;
  const uint4* pr = (const uint4*)(part + (size_t)p * NSUB * 8192);
  for (int idx = t; idx < 1024; idx += 256) {
    int a0=0,a1=0,a2=0,a3=0,a4=0,a5=0,a6=0,a7=0;
#pragma unroll
    for (int s = 0; s < NSUB; ++s) {
      uint4 v = pr[(size_t)s * 1024 + idx];
      a0 += (int)(v.x & 0xffff); a1 += (int)(v.x >> 16);
      a2 += (int)(v.y & 0xffff); a3 += (int)(v.y >> 16);
      a4 += (int)(v.z & 0xffff); a5 += (int)(v.z >> 16);
      a6 += (int)(v.w & 0xffff); a7 += (int)(v.w >> 16);
    }
    int* hb = &hsum[idx * 8];
    hb[0]=a0; hb[1]=a1; hb[2]=a2; hb[3]=a3; hb[4]=a4; hb[5]=a5; hb[6]=a6; hb[7]=a7;
  }
  __syncthreads();
  int mysum = 0;
#pragma unroll
  for (int j = 0; j < 32; j += 4) {
    int4 v = *(const int4*)&hsum[t * 32 + j];
    mysum += v.x + v.y + v.z + v.w;
  }
  incl[t] = mysum;
  __syncthreads();
  for (int off = 1; off < 256; off <<= 1) {
    int v = (t >= off) ? incl[t - off] : 0;
    __syncthreads();
    incl[t] += v;
    __syncthreads();
  }
  // 1-based ranks: lo -> 7865,7866 (frac .29); hi -> 254279,254280 (frac .71)
  const int ranks[4] = {7865, 7866, 254279, 254280};
#pragma unroll
  for (int r = 0; r < 4; ++r) {
    const int rank = ranks[r];
    int excl = incl[t] - mysum;
    if (excl < rank && rank <= incl[t]) { s_chunk = t; s_base = rank - excl; }
    __syncthreads();
    if (t < 64) {
      const int c = s_chunk, base = s_base;
      int cnt = (t < 32) ? hsum[c * 32 + t] : 0;
      int pfx = cnt;
#pragma unroll
      for (int off = 1; off < 32; off <<= 1) {
        int u = __shfl_up(pfx, off, 64);
        if (t >= off) pfx += u;
      }
      unsigned long long m = __ballot(t < 32 && pfx >= base);
      int bin = c * 32 + (__ffsll((long long)m) - 1);
      if (t == 0) s_v[r] = (float)(bin - 4096) * 0.00390625f;
    }
    __syncthreads();
  }
  if (t == 0) {
    const double fl = 0.29, fh = 0.71;
    double lov = (double)s_v[0] + fl * ((double)s_v[1] - (double)s_v[0]);
    double hiv = (double)s_v[2] + fh * ((double)s_v[3] - (double)s_v[2]);
    lo_out[p] = (float)lov;
    inv_out[p] = (float)(1.0 / (hiv - lov));
  }
}

// ---------- final normalize in place, 4 float4/thread, XCD-affine to res writer ----------
__global__ __launch_bounds__(256) void final_kernel(float* __restrict__ res,
                                                    const float* __restrict__ mask,
                                                    const float* __restrict__ lo,
                                                    const float* __restrict__ inv) {
  const int b = blockIdx.x;               // 3072
  const int xcd = b & 7, idx = b >> 3;    // idx 0..383
  const int z = xcd * 6 + (idx >> 6);     // 6 planes per XCD, 64 blocks/plane
  const int chunk = idx & 63;
  const int n = z / NCH;
  const int base = z * 65536 + chunk * 1024 + threadIdx.x;  // f4 units
  const int h0 = base & 65535;
  float4* rz = (float4*)res;
  const float4* mz = (const float4*)mask + (size_t)n * 65536;
  float4 r0 = rz[base],       r1 = rz[base + 256],
         r2 = rz[base + 512], r3 = rz[base + 768];
  float4 m0 = mz[h0],       m1 = mz[h0 + 256],
         m2 = mz[h0 + 512], m3 = mz[h0 + 768];
  const float l = lo[z];
  const float iv = inv[z];
  float4 o0, o1, o2, o3;
  o0.x = (r0.x - l) * iv * m0.x;  o0.y = (r0.y - l) * iv * m0.y;
  o0.z = (r0.z - l) * iv * m0.z;  o0.w = (r0.w - l) * iv * m0.w;
  o1.x = (r1.x - l) * iv * m1.x;  o1.y = (r1.y - l) * iv * m1.y;
  o1.z = (r1.z - l) * iv * m1.z;  o1.w = (r1.w - l) * iv * m1.w;
  o2.x = (r2.x - l) * iv * m2.x;  o2.y = (r2.y - l) * iv * m2.y;
  o2.z = (r2.z - l) * iv * m2.z;  o2.w = (r2.w - l) * iv * m2.w;
  o3.x = (r3.x - l) * iv * m3.x;  o3.y = (r3.y - l) * iv * m3.y;
  o3.z = (r3.z - l) * iv * m3.z;  o3.w = (r3.w - l) * iv * m3.w;
  rz[base] = o0;
  rz[base + 256] = o1;
  rz[base + 512] = o2;
  rz[base + 768] = o3;
}

extern "C" void kernel_launch(void* const* d_in, const int* in_sizes, int n_in,
                              void* d_out, int out_size, void* d_ws, size_t ws_size,
                              hipStream_t stream) {
  (void)in_sizes; (void)n_in; (void)out_size; (void)ws_size;
  const float* x = (const float*)d_in[0];
  const float* mask = (const float*)d_in[1];
  const float* kern = (const float*)d_in[2];
  float* out = (float*)d_out;  // doubles as res scratch

  // partial histograms: PLANES*NSUB rows of 8192 u16 = 12.58 MB, reused by both stages
  ushort* part = (ushort*)d_ws;
  float* med = (float*)(part + (size_t)PLANES * NSUB * 8192);
  float* lo = med + PLANES;
  float* inv = lo + PLANES;
  float* k1g = inv + PLANES;              // 23 floats

  hist1_kernel<<<dim3(PLANES, NSUB), 512, 0, stream>>>(x, part);
  scan_med_kernel<<<PLANES, 256, 0, stream>>>(part, med, kern, k1g);
  conv_kernel<<<dim3(3072), 256, 0, stream>>>(x, mask, k1g, med, out);
  hist_kernel<<<dim3(768), 512, 0, stream>>>(out, part);
  pct_kernel<<<PLANES, 256, 0, stream>>>(part, lo, inv);
  final_kernel<<<dim3(3072), 256, 0, stream>>>(out, mask, lo, inv);
}